// Round 3
// baseline (4883.704 us; speedup 1.0000x reference)
//
#include <hip/hip_runtime.h>
#include <math.h>

// ---------------------------------------------------------------------------
// FeatureEncoder R3: LDS-tiled convs; instance-norm fully fused
//  (stats via per-conv atomic reduction, apply via staging-time normalize).
//  L0 conv7x7 reflect3   3->32   256          (raw input, no norm)
//  L1-L3 conv3x3 s2 p1   (norm+relu of prev fused into staging)
//  L4-L6 convT3x3 s2 p1  (quad form, norm+relu fused into staging)
//  L7 conv7x7 reflect3  32->3, tanh (norm+relu fused; no stats out)
//  segment mean over 32 instance ids
// ---------------------------------------------------------------------------

#define IDIV(a, b) (((a) + (b) - 1) / (b))

__device__ __forceinline__ int reflect_i(int i, int n) {
    i = i < 0 ? -i : i;
    return i >= n ? 2 * n - 2 - i : i;
}

// per-wave reduce of (sum, sumsq) for OCPT channels, atomic into global
template <int OCPT>
__device__ __forceinline__ void stats_atomic(const float* sv, const float* ssv,
                                             float* __restrict__ osum,
                                             float* __restrict__ osumsq, int pc0) {
    int lane = threadIdx.x & 63;
#pragma unroll
    for (int j = 0; j < OCPT; ++j) {
        float s = sv[j], ss = ssv[j];
#pragma unroll
        for (int o = 32; o > 0; o >>= 1) {
            s += __shfl_down(s, o);
            ss += __shfl_down(ss, o);
        }
        if (lane == 0) {
            atomicAdd(&osum[pc0 + j], s);
            atomicAdd(&osumsq[pc0 + j], ss);
        }
    }
}

// ---------------- 7x7 same-conv, reflect pad 3, LDS-tiled ----------------
template <int CIN, int ICB, int OCPT, bool NORM, bool TANH>
__global__ __launch_bounds__(256) void conv7x7(
    const float* __restrict__ x, const float* __restrict__ w,
    const float* __restrict__ b, float* __restrict__ y,
    const float* __restrict__ in_s, const float* __restrict__ in_ss,
    float rcp_plane_in, int in_off,
    float* __restrict__ out_s, float* __restrict__ out_ss, int out_off,
    int Cout, int H, int W) {
    constexpr int ICST = 22 * 23;  // 22 rows x 22 cols, stride 23
    __shared__ float tile[ICB * ICST];
    int tx = threadIdx.x & 15, ty = threadIdx.x >> 4;
    int tilesX = IDIV(W, 16);
    int bx = blockIdx.x % tilesX, by = blockIdx.x / tilesX;
    int ow = bx * 16 + tx, oh = by * 16 + ty;
    int oc0 = blockIdx.y * OCPT, n = blockIdx.z;
    bool valid = (ow < W) && (oh < H);

    float acc[OCPT];
#pragma unroll
    for (int j = 0; j < OCPT; ++j) acc[j] = 0.f;

    for (int ic0 = 0; ic0 < CIN; ic0 += ICB) {
        __syncthreads();
        // stage ICB input planes (reflect-indexed), optional norm+relu
        for (int icl = 0; icl < ICB; ++icl) {
            int ic = ic0 + icl;
            float m = 0.f, iv = 1.f;
            if (NORM) {
                int pc = in_off + n * CIN + ic;
                m = in_s[pc] * rcp_plane_in;
                iv = rsqrtf(in_ss[pc] * rcp_plane_in - m * m + 1e-5f);
            }
            const float* base = x + (size_t)(n * CIN + ic) * H * W;
            for (int t = threadIdx.x; t < 484; t += 256) {
                int r = t / 22, c = t % 22;
                int gr = reflect_i(by * 16 - 3 + r, H);
                int gc = reflect_i(bx * 16 - 3 + c, W);
                float raw = base[(size_t)gr * W + gc];
                tile[icl * ICST + r * 23 + c] = NORM ? fmaxf(0.f, (raw - m) * iv) : raw;
            }
        }
        __syncthreads();
#pragma unroll
        for (int icl = 0; icl < ICB; ++icl) {
            const float* wp = w + ((size_t)oc0 * CIN + ic0 + icl) * 49;
#pragma unroll
            for (int kh = 0; kh < 7; ++kh) {
#pragma unroll
                for (int kw = 0; kw < 7; ++kw) {
                    float v = tile[icl * ICST + (ty + kh) * 23 + tx + kw];
#pragma unroll
                    for (int j = 0; j < OCPT; ++j)
                        acc[j] += v * wp[(size_t)j * CIN * 49 + kh * 7 + kw];
                }
            }
        }
    }

    float sv[OCPT], ssv[OCPT];
#pragma unroll
    for (int j = 0; j < OCPT; ++j) {
        float r = acc[j] + b[oc0 + j];
        if (TANH) r = tanhf(r);
        sv[j] = valid ? r : 0.f;
        ssv[j] = valid ? r * r : 0.f;
        if (valid) y[((size_t)(n * Cout + oc0 + j) * H + oh) * W + ow] = r;
    }
    if (!TANH) stats_atomic<OCPT>(sv, ssv, out_s, out_ss, out_off + n * Cout + oc0);
}

// ---------------- 3x3 stride-2 pad-1 conv, LDS-tiled ----------------
// LDS layout per ic: 33 rows, row stride 40, cols parity-split
//   (even cols at [0..16], odd cols at [20..36]) so compute reads
//   (stride-2 in input cols) hit banks exactly 2-way (free).
template <int CIN, int ICB, int OCPT>
__global__ __launch_bounds__(256) void conv3s2(
    const float* __restrict__ x, const float* __restrict__ w,
    const float* __restrict__ b, float* __restrict__ y,
    const float* __restrict__ in_s, const float* __restrict__ in_ss,
    float rcp_plane_in, int in_off,
    float* __restrict__ out_s, float* __restrict__ out_ss, int out_off,
    int Cout, int Hin, int Win, int Hout, int Wout) {
    constexpr int ICST = 33 * 40;
    __shared__ float tile[ICB * ICST];
    int tx = threadIdx.x & 15, ty = threadIdx.x >> 4;
    int tilesX = Wout >> 4;
    int bx = blockIdx.x % tilesX, by = blockIdx.x / tilesX;
    int ow = bx * 16 + tx, oh = by * 16 + ty;
    int oc0 = blockIdx.y * OCPT, n = blockIdx.z;
    int r0 = by * 32 - 1, c0 = bx * 32 - 1;

    float acc[OCPT];
#pragma unroll
    for (int j = 0; j < OCPT; ++j) acc[j] = 0.f;

    for (int ic0 = 0; ic0 < CIN; ic0 += ICB) {
        __syncthreads();
        for (int icl = 0; icl < ICB; ++icl) {
            int ic = ic0 + icl;
            int pc = in_off + n * CIN + ic;
            float m = in_s[pc] * rcp_plane_in;
            float iv = rsqrtf(in_ss[pc] * rcp_plane_in - m * m + 1e-5f);
            const float* base = x + (size_t)(n * CIN + ic) * Hin * Win;
            for (int t = threadIdx.x; t < 1089; t += 256) {
                int r = t / 33, c = t % 33;
                int gr = r0 + r, gc = c0 + c;
                float v = 0.f;
                if (gr >= 0 && gr < Hin && gc >= 0 && gc < Win)
                    v = fmaxf(0.f, (base[(size_t)gr * Win + gc] - m) * iv);
                tile[icl * ICST + r * 40 + (c & 1) * 20 + (c >> 1)] = v;
            }
        }
        __syncthreads();
#pragma unroll
        for (int icl = 0; icl < ICB; ++icl) {
            const float* wp = w + ((size_t)oc0 * CIN + ic0 + icl) * 9;
#pragma unroll
            for (int kh = 0; kh < 3; ++kh) {
#pragma unroll
                for (int kw = 0; kw < 3; ++kw) {
                    float v = tile[icl * ICST + (2 * ty + kh) * 40 + (kw & 1) * 20 + tx + (kw >> 1)];
#pragma unroll
                    for (int j = 0; j < OCPT; ++j)
                        acc[j] += v * wp[(size_t)j * CIN * 9 + kh * 3 + kw];
                }
            }
        }
    }

    float sv[OCPT], ssv[OCPT];
#pragma unroll
    for (int j = 0; j < OCPT; ++j) {
        float r = acc[j] + b[oc0 + j];
        sv[j] = r;
        ssv[j] = r * r;
        y[((size_t)(n * Cout + oc0 + j) * Hout + oh) * Wout + ow] = r;
    }
    stats_atomic<OCPT>(sv, ssv, out_s, out_ss, out_off + n * Cout + oc0);
}

// ---------------- 3x3 stride-2 transposed conv, quad form, LDS-tiled --------
template <int CIN, int ICB, int OCPT>
__global__ __launch_bounds__(256) void convt3s2(
    const float* __restrict__ x, const float* __restrict__ w,
    const float* __restrict__ b, float* __restrict__ y,
    const float* __restrict__ in_s, const float* __restrict__ in_ss,
    float rcp_plane_in, int in_off,
    float* __restrict__ out_s, float* __restrict__ out_ss, int out_off,
    int Cout, int Hin, int Win, int Hout, int Wout) {
    constexpr int ICST = 17 * 18;  // 17x17 patch, stride 18
    __shared__ float tile[ICB * ICST];
    int tx = threadIdx.x & 15, ty = threadIdx.x >> 4;
    int tilesX = IDIV(Win, 16);
    int bx = blockIdx.x % tilesX, by = blockIdx.x / tilesX;
    int qx0 = bx * 16, qy0 = by * 16;
    int qx = qx0 + tx, qy = qy0 + ty;
    int oc0 = blockIdx.y * OCPT, n = blockIdx.z;
    bool valid = (qx < Win) && (qy < Hin);
    bool xin = (qx + 1 < Win), yin = (qy + 1 < Hin);

    float a00[OCPT], a01[OCPT], a10[OCPT], a11[OCPT];
#pragma unroll
    for (int j = 0; j < OCPT; ++j) { a00[j] = a01[j] = a10[j] = a11[j] = 0.f; }

    for (int ic0 = 0; ic0 < CIN; ic0 += ICB) {
        __syncthreads();
        for (int icl = 0; icl < ICB; ++icl) {
            int ic = ic0 + icl;
            int pc = in_off + n * CIN + ic;
            float m = in_s[pc] * rcp_plane_in;
            float iv = rsqrtf(in_ss[pc] * rcp_plane_in - m * m + 1e-5f);
            const float* base = x + (size_t)(n * CIN + ic) * Hin * Win;
            for (int t = threadIdx.x; t < 289; t += 256) {
                int r = t / 17, c = t % 17;
                int gr = qy0 + r, gc = qx0 + c;
                float v = 0.f;
                if (gr < Hin && gc < Win)
                    v = fmaxf(0.f, (base[(size_t)gr * Win + gc] - m) * iv);
                tile[icl * ICST + r * 18 + c] = v;
            }
        }
        __syncthreads();
#pragma unroll
        for (int icl = 0; icl < ICB; ++icl) {
            float v00 = tile[icl * ICST + ty * 18 + tx];
            float v01 = tile[icl * ICST + ty * 18 + tx + 1];
            float v10 = tile[icl * ICST + (ty + 1) * 18 + tx];
            float v11 = tile[icl * ICST + (ty + 1) * 18 + tx + 1];
            const float* wp = w + ((size_t)(ic0 + icl) * Cout + oc0) * 9;
#pragma unroll
            for (int j = 0; j < OCPT; ++j) {
                const float* wj = wp + j * 9;
                a00[j] += wj[4] * v00;
                a01[j] += wj[5] * v00 + wj[3] * v01;
                a10[j] += wj[7] * v00 + wj[1] * v10;
                a11[j] += wj[8] * v00 + wj[6] * v01 + wj[2] * v10 + wj[0] * v11;
            }
        }
    }

    int oh = 2 * qy, ow = 2 * qx;
    float sv[OCPT], ssv[OCPT];
#pragma unroll
    for (int j = 0; j < OCPT; ++j) {
        float s = 0.f, ss = 0.f;
        if (valid) {
            float bb = b[oc0 + j];
            float* yp = y + (((size_t)(n * Cout + oc0 + j)) * Hout + oh) * Wout + ow;
            float t00 = a00[j] + bb;
            yp[0] = t00; s = t00; ss = t00 * t00;
            if (xin) { float t = a01[j] + bb; yp[1] = t; s += t; ss += t * t; }
            if (yin) { float t = a10[j] + bb; yp[Wout] = t; s += t; ss += t * t; }
            if (xin && yin) { float t = a11[j] + bb; yp[Wout + 1] = t; s += t; ss += t * t; }
        }
        sv[j] = s; ssv[j] = ss;
    }
    stats_atomic<OCPT>(sv, ssv, out_s, out_ss, out_off + n * Cout + oc0);
}

// ---------------- misc ----------------
__global__ void zero_buf(float* __restrict__ p, int n) {
    int i = blockIdx.x * 256 + threadIdx.x;
    if (i < n) p[i] = 0.f;
}

__global__ void seg_accum(const float* __restrict__ a7, const int* __restrict__ inst,
                          float* __restrict__ bins, int HW) {
    __shared__ float ls[128];  // 96 sums + 32 counts
    for (int i = threadIdx.x; i < 128; i += 256) ls[i] = 0.f;
    __syncthreads();
    int n = blockIdx.y;
    int i = blockIdx.x * 256 + threadIdx.x;
    if (i < HW) {
        int id = inst[(size_t)n * HW + i];
        const float* p = a7 + (size_t)n * 3 * HW + i;
        atomicAdd(&ls[id * 3 + 0], p[0]);
        atomicAdd(&ls[id * 3 + 1], p[HW]);
        atomicAdd(&ls[id * 3 + 2], p[2 * (size_t)HW]);
        atomicAdd(&ls[96 + id], 1.0f);
    }
    __syncthreads();
    for (int i2 = threadIdx.x; i2 < 128; i2 += 256)
        if (ls[i2] != 0.f) atomicAdd(&bins[i2], ls[i2]);
}

__global__ void seg_scatter(const float* __restrict__ bins, const int* __restrict__ inst,
                            float* __restrict__ out, int HW) {
    int n = blockIdx.y;
    int i = blockIdx.x * 256 + threadIdx.x;
    if (i >= HW) return;
    int id = inst[(size_t)n * HW + i];
    float c = fmaxf(bins[96 + id], 1.0f);
    out[((size_t)n * 3 + 0) * HW + i] = bins[id * 3 + 0] / c;
    out[((size_t)n * 3 + 1) * HW + i] = bins[id * 3 + 1] / c;
    out[((size_t)n * 3 + 2) * HW + i] = bins[id * 3 + 2] / c;
}

// ---------------------------------------------------------------------------
extern "C" void kernel_launch(void* const* d_in, const int* in_sizes, int n_in,
                              void* d_out, int out_size, void* d_ws, size_t ws_size,
                              hipStream_t stream) {
    const float* x = (const float*)d_in[0];
    const int* inst = (const int*)d_in[1];
    const float* W[8];
    const float* B[8];
    for (int i = 0; i < 8; ++i) {
        W[i] = (const float*)d_in[2 + 2 * i];
        B[i] = (const float*)d_in[3 + 2 * i];
    }
    float* ws = (float*)d_ws;

    // activation arena (end-aligned ping-pong), then stats sums + bins
    const size_t S = 25165824;  // floats
    float* a0 = ws;
    float* a1 = ws + 16777216;
    float* a2 = ws;
    float* a3 = ws + 23068672;
    float* a4 = ws;
    float* a5 = ws + 17165824;
    float* a6 = ws;
    float* a7 = ws + 23677800;
    float* ssum = ws + S;          // 5632 (per-layer plane sums, offsets below)
    float* sssum = ssum + 5632;    // 5632
    float* bins = sssum + 5632;    // 128
    // per-layer plane-count offsets into ssum/sssum
    const int OFF0 = 0, OFF1 = 256, OFF2 = 768, OFF3 = 1792, OFF4 = 3840, OFF5 = 4864, OFF6 = 5376;

    zero_buf<<<dim3(IDIV(11520, 256)), 256, 0, stream>>>(ssum, 11520);

    // L0: 7x7 reflect, 3->32, 256 (raw input)
    conv7x7<3, 3, 8, false, false><<<dim3(256, 4, 8), 256, 0, stream>>>(
        x, W[0], B[0], a0, nullptr, nullptr, 0.f, 0, ssum, sssum, OFF0, 32, 256, 256);
    // L1: 3x3 s2, 32->64, 256->128
    conv3s2<32, 4, 8><<<dim3(64, 8, 8), 256, 0, stream>>>(
        a0, W[1], B[1], a1, ssum, sssum, 1.f / 65536.f, OFF0, ssum, sssum, OFF1,
        64, 256, 256, 128, 128);
    // L2: 3x3 s2, 64->128, 128->64
    conv3s2<64, 4, 8><<<dim3(16, 16, 8), 256, 0, stream>>>(
        a1, W[2], B[2], a2, ssum, sssum, 1.f / 16384.f, OFF1, ssum, sssum, OFF2,
        128, 128, 128, 64, 64);
    // L3: 3x3 s2, 128->256, 64->32
    conv3s2<128, 4, 8><<<dim3(4, 32, 8), 256, 0, stream>>>(
        a2, W[3], B[3], a3, ssum, sssum, 1.f / 4096.f, OFF2, ssum, sssum, OFF3,
        256, 64, 64, 32, 32);
    // L4: convT, 256->128, 32->63
    convt3s2<256, 16, 8><<<dim3(4, 16, 8), 256, 0, stream>>>(
        a3, W[4], B[4], a4, ssum, sssum, 1.f / 1024.f, OFF3, ssum, sssum, OFF4,
        128, 32, 32, 63, 63);
    // L5: convT, 128->64, 63->125
    convt3s2<128, 8, 8><<<dim3(16, 8, 8), 256, 0, stream>>>(
        a4, W[5], B[5], a5, ssum, sssum, 1.f / 3969.f, OFF4, ssum, sssum, OFF5,
        64, 63, 63, 125, 125);
    // L6: convT, 64->32, 125->249
    convt3s2<64, 8, 8><<<dim3(64, 4, 8), 256, 0, stream>>>(
        a5, W[6], B[6], a6, ssum, sssum, 1.f / 15625.f, OFF5, ssum, sssum, OFF6,
        32, 125, 125, 249, 249);
    // L7: 7x7 reflect, 32->3, 249, norm-in + tanh
    conv7x7<32, 8, 3, true, true><<<dim3(256, 1, 8), 256, 0, stream>>>(
        a6, W[7], B[7], a7, ssum, sssum, 1.f / 62001.f, OFF6, nullptr, nullptr, 0,
        3, 249, 249);

    // segment mean (bins zeroed by zero_buf above)
    seg_accum<<<dim3(IDIV(62001, 256), 8), 256, 0, stream>>>(a7, inst, bins, 62001);
    seg_scatter<<<dim3(IDIV(62001, 256), 8), 256, 0, stream>>>(bins, inst, (float*)d_out, 62001);
}

// Round 4
// 3228.841 us; speedup vs baseline: 1.5125x; 1.5125x over previous
//
#include <hip/hip_runtime.h>
#include <math.h>

// ---------------------------------------------------------------------------
// FeatureEncoder R4: LDS-tiled convs; instance-norm fused WITHOUT atomics.
//  Producer conv blocks write per-(tile,plane) stat partials (plain stores);
//  a tiny stat_reduce kernel folds them into ssum/sssum; consumer normalizes
//  at staging time. R3's device-atomic stats caused per-line RMW serialization
//  (~85ns/atomic, 16 chans/line) -> 1.4ms on L0 alone. No global atomics here.
// ---------------------------------------------------------------------------

#define IDIV(a, b) (((a) + (b) - 1) / (b))

__device__ __forceinline__ int reflect_i(int i, int n) {
    i = i < 0 ? -i : i;
    return i >= n ? 2 * n - 2 - i : i;
}

// block-level (sum,sumsq) reduction for OCPT channels -> partial store
template <int OCPT>
__device__ __forceinline__ void stats_block_store(
    const float* sv, const float* ssv, float* __restrict__ spart,
    float* __restrict__ sspart, int P, int tile, int pc0) {
    __shared__ float redS[OCPT], redSS[OCPT];
    if (threadIdx.x < OCPT) { redS[threadIdx.x] = 0.f; redSS[threadIdx.x] = 0.f; }
    __syncthreads();
    int lane = threadIdx.x & 63;
#pragma unroll
    for (int j = 0; j < OCPT; ++j) {
        float s = sv[j], ss = ssv[j];
#pragma unroll
        for (int o = 32; o > 0; o >>= 1) {
            s += __shfl_down(s, o);
            ss += __shfl_down(ss, o);
        }
        if (lane == 0) { atomicAdd(&redS[j], s); atomicAdd(&redSS[j], ss); }  // LDS atomics
    }
    __syncthreads();
    if (threadIdx.x < OCPT) {
        spart[(size_t)tile * P + pc0 + threadIdx.x] = redS[threadIdx.x];
        sspart[(size_t)tile * P + pc0 + threadIdx.x] = redSS[threadIdx.x];
    }
}

// fold [nT][P] partials into ssum/sssum; one wavefront per plane
__global__ __launch_bounds__(64) void stat_reduce(
    const float* __restrict__ sp, const float* __restrict__ ssp,
    float* __restrict__ s, float* __restrict__ ss, int P, int nT, int off) {
    int p = blockIdx.x;
    float a = 0.f, b = 0.f;
    for (int t = threadIdx.x; t < nT; t += 64) {
        a += sp[(size_t)t * P + p];
        b += ssp[(size_t)t * P + p];
    }
#pragma unroll
    for (int o = 32; o > 0; o >>= 1) {
        a += __shfl_down(a, o);
        b += __shfl_down(b, o);
    }
    if (threadIdx.x == 0) { s[off + p] = a; ss[off + p] = b; }
}

// ---------------- 7x7 same-conv, reflect pad 3, LDS-tiled ----------------
template <int CIN, int ICB, int OCPT, bool NORM, bool TANH>
__global__ __launch_bounds__(256) void conv7x7(
    const float* __restrict__ x, const float* __restrict__ w,
    const float* __restrict__ b, float* __restrict__ y,
    const float* __restrict__ in_s, const float* __restrict__ in_ss,
    float rcp_plane_in, int in_off,
    float* __restrict__ spart, float* __restrict__ sspart, int P,
    int Cout, int H, int W) {
    constexpr int ICST = 22 * 23;
    __shared__ float tile[ICB * ICST];
    int tx = threadIdx.x & 15, ty = threadIdx.x >> 4;
    int tilesX = IDIV(W, 16);
    int bx = blockIdx.x % tilesX, by = blockIdx.x / tilesX;
    int ow = bx * 16 + tx, oh = by * 16 + ty;
    int oc0 = blockIdx.y * OCPT, n = blockIdx.z;
    bool valid = (ow < W) && (oh < H);

    float acc[OCPT];
#pragma unroll
    for (int j = 0; j < OCPT; ++j) acc[j] = 0.f;

    for (int ic0 = 0; ic0 < CIN; ic0 += ICB) {
        __syncthreads();
        for (int icl = 0; icl < ICB; ++icl) {
            int ic = ic0 + icl;
            float m = 0.f, iv = 1.f;
            if (NORM) {
                int pc = in_off + n * CIN + ic;
                m = in_s[pc] * rcp_plane_in;
                iv = rsqrtf(in_ss[pc] * rcp_plane_in - m * m + 1e-5f);
            }
            const float* base = x + (size_t)(n * CIN + ic) * H * W;
            for (int t = threadIdx.x; t < 484; t += 256) {
                int r = t / 22, c = t % 22;
                int gr = reflect_i(by * 16 - 3 + r, H);
                int gc = reflect_i(bx * 16 - 3 + c, W);
                float raw = base[(size_t)gr * W + gc];
                tile[icl * ICST + r * 23 + c] = NORM ? fmaxf(0.f, (raw - m) * iv) : raw;
            }
        }
        __syncthreads();
#pragma unroll
        for (int icl = 0; icl < ICB; ++icl) {
            const float* wp = w + ((size_t)oc0 * CIN + ic0 + icl) * 49;
#pragma unroll
            for (int kh = 0; kh < 7; ++kh) {
#pragma unroll
                for (int kw = 0; kw < 7; ++kw) {
                    float v = tile[icl * ICST + (ty + kh) * 23 + tx + kw];
#pragma unroll
                    for (int j = 0; j < OCPT; ++j)
                        acc[j] += v * wp[(size_t)j * CIN * 49 + kh * 7 + kw];
                }
            }
        }
    }

    float sv[OCPT], ssv[OCPT];
#pragma unroll
    for (int j = 0; j < OCPT; ++j) {
        float r = acc[j] + b[oc0 + j];
        if (TANH) r = tanhf(r);
        sv[j] = valid ? r : 0.f;
        ssv[j] = valid ? r * r : 0.f;
        if (valid) y[((size_t)(n * Cout + oc0 + j) * H + oh) * W + ow] = r;
    }
    if (!TANH)
        stats_block_store<OCPT>(sv, ssv, spart, sspart, P, blockIdx.x, n * Cout + oc0);
}

// ---------------- 3x3 stride-2 pad-1 conv, LDS-tiled ----------------
template <int CIN, int ICB, int OCPT>
__global__ __launch_bounds__(256) void conv3s2(
    const float* __restrict__ x, const float* __restrict__ w,
    const float* __restrict__ b, float* __restrict__ y,
    const float* __restrict__ in_s, const float* __restrict__ in_ss,
    float rcp_plane_in, int in_off,
    float* __restrict__ spart, float* __restrict__ sspart, int P,
    int Cout, int Hin, int Win, int Hout, int Wout) {
    constexpr int ICST = 33 * 40;
    __shared__ float tile[ICB * ICST];
    int tx = threadIdx.x & 15, ty = threadIdx.x >> 4;
    int tilesX = Wout >> 4;
    int bx = blockIdx.x % tilesX, by = blockIdx.x / tilesX;
    int ow = bx * 16 + tx, oh = by * 16 + ty;
    int oc0 = blockIdx.y * OCPT, n = blockIdx.z;
    int r0 = by * 32 - 1, c0 = bx * 32 - 1;

    float acc[OCPT];
#pragma unroll
    for (int j = 0; j < OCPT; ++j) acc[j] = 0.f;

    for (int ic0 = 0; ic0 < CIN; ic0 += ICB) {
        __syncthreads();
        for (int icl = 0; icl < ICB; ++icl) {
            int ic = ic0 + icl;
            int pc = in_off + n * CIN + ic;
            float m = in_s[pc] * rcp_plane_in;
            float iv = rsqrtf(in_ss[pc] * rcp_plane_in - m * m + 1e-5f);
            const float* base = x + (size_t)(n * CIN + ic) * Hin * Win;
            for (int t = threadIdx.x; t < 1089; t += 256) {
                int r = t / 33, c = t % 33;
                int gr = r0 + r, gc = c0 + c;
                float v = 0.f;
                if (gr >= 0 && gr < Hin && gc >= 0 && gc < Win)
                    v = fmaxf(0.f, (base[(size_t)gr * Win + gc] - m) * iv);
                tile[icl * ICST + r * 40 + (c & 1) * 20 + (c >> 1)] = v;
            }
        }
        __syncthreads();
#pragma unroll
        for (int icl = 0; icl < ICB; ++icl) {
            const float* wp = w + ((size_t)oc0 * CIN + ic0 + icl) * 9;
#pragma unroll
            for (int kh = 0; kh < 3; ++kh) {
#pragma unroll
                for (int kw = 0; kw < 3; ++kw) {
                    float v = tile[icl * ICST + (2 * ty + kh) * 40 + (kw & 1) * 20 + tx + (kw >> 1)];
#pragma unroll
                    for (int j = 0; j < OCPT; ++j)
                        acc[j] += v * wp[(size_t)j * CIN * 9 + kh * 3 + kw];
                }
            }
        }
    }

    float sv[OCPT], ssv[OCPT];
#pragma unroll
    for (int j = 0; j < OCPT; ++j) {
        float r = acc[j] + b[oc0 + j];
        sv[j] = r;
        ssv[j] = r * r;
        y[((size_t)(n * Cout + oc0 + j) * Hout + oh) * Wout + ow] = r;
    }
    stats_block_store<OCPT>(sv, ssv, spart, sspart, P, blockIdx.x, n * Cout + oc0);
}

// ---------------- 3x3 stride-2 transposed conv, quad form, LDS-tiled --------
template <int CIN, int ICB, int OCPT>
__global__ __launch_bounds__(256) void convt3s2(
    const float* __restrict__ x, const float* __restrict__ w,
    const float* __restrict__ b, float* __restrict__ y,
    const float* __restrict__ in_s, const float* __restrict__ in_ss,
    float rcp_plane_in, int in_off,
    float* __restrict__ spart, float* __restrict__ sspart, int P,
    int Cout, int Hin, int Win, int Hout, int Wout) {
    constexpr int ICST = 17 * 18;
    __shared__ float tile[ICB * ICST];
    int tx = threadIdx.x & 15, ty = threadIdx.x >> 4;
    int tilesX = IDIV(Win, 16);
    int bx = blockIdx.x % tilesX, by = blockIdx.x / tilesX;
    int qx0 = bx * 16, qy0 = by * 16;
    int qx = qx0 + tx, qy = qy0 + ty;
    int oc0 = blockIdx.y * OCPT, n = blockIdx.z;
    bool valid = (qx < Win) && (qy < Hin);
    bool xin = (qx + 1 < Win), yin = (qy + 1 < Hin);

    float a00[OCPT], a01[OCPT], a10[OCPT], a11[OCPT];
#pragma unroll
    for (int j = 0; j < OCPT; ++j) { a00[j] = a01[j] = a10[j] = a11[j] = 0.f; }

    for (int ic0 = 0; ic0 < CIN; ic0 += ICB) {
        __syncthreads();
        for (int icl = 0; icl < ICB; ++icl) {
            int ic = ic0 + icl;
            int pc = in_off + n * CIN + ic;
            float m = in_s[pc] * rcp_plane_in;
            float iv = rsqrtf(in_ss[pc] * rcp_plane_in - m * m + 1e-5f);
            const float* base = x + (size_t)(n * CIN + ic) * Hin * Win;
            for (int t = threadIdx.x; t < 289; t += 256) {
                int r = t / 17, c = t % 17;
                int gr = qy0 + r, gc = qx0 + c;
                float v = 0.f;
                if (gr < Hin && gc < Win)
                    v = fmaxf(0.f, (base[(size_t)gr * Win + gc] - m) * iv);
                tile[icl * ICST + r * 18 + c] = v;
            }
        }
        __syncthreads();
#pragma unroll
        for (int icl = 0; icl < ICB; ++icl) {
            float v00 = tile[icl * ICST + ty * 18 + tx];
            float v01 = tile[icl * ICST + ty * 18 + tx + 1];
            float v10 = tile[icl * ICST + (ty + 1) * 18 + tx];
            float v11 = tile[icl * ICST + (ty + 1) * 18 + tx + 1];
            const float* wp = w + ((size_t)(ic0 + icl) * Cout + oc0) * 9;
#pragma unroll
            for (int j = 0; j < OCPT; ++j) {
                const float* wj = wp + j * 9;
                a00[j] += wj[4] * v00;
                a01[j] += wj[5] * v00 + wj[3] * v01;
                a10[j] += wj[7] * v00 + wj[1] * v10;
                a11[j] += wj[8] * v00 + wj[6] * v01 + wj[2] * v10 + wj[0] * v11;
            }
        }
    }

    int oh = 2 * qy, ow = 2 * qx;
    float sv[OCPT], ssv[OCPT];
#pragma unroll
    for (int j = 0; j < OCPT; ++j) {
        float s = 0.f, ss = 0.f;
        if (valid) {
            float bb = b[oc0 + j];
            float* yp = y + (((size_t)(n * Cout + oc0 + j)) * Hout + oh) * Wout + ow;
            float t00 = a00[j] + bb;
            yp[0] = t00; s = t00; ss = t00 * t00;
            if (xin) { float t = a01[j] + bb; yp[1] = t; s += t; ss += t * t; }
            if (yin) { float t = a10[j] + bb; yp[Wout] = t; s += t; ss += t * t; }
            if (xin && yin) { float t = a11[j] + bb; yp[Wout + 1] = t; s += t; ss += t * t; }
        }
        sv[j] = s; ssv[j] = ss;
    }
    stats_block_store<OCPT>(sv, ssv, spart, sspart, P, blockIdx.x, n * Cout + oc0);
}

// ---------------- misc ----------------
__global__ void zero_buf(float* __restrict__ p, int n) {
    int i = blockIdx.x * 256 + threadIdx.x;
    if (i < n) p[i] = 0.f;
}

__global__ void seg_accum(const float* __restrict__ a7, const int* __restrict__ inst,
                          float* __restrict__ bins, int HW) {
    __shared__ float ls[128];
    for (int i = threadIdx.x; i < 128; i += 256) ls[i] = 0.f;
    __syncthreads();
    int n = blockIdx.y;
    int i = blockIdx.x * 256 + threadIdx.x;
    if (i < HW) {
        int id = inst[(size_t)n * HW + i];
        const float* p = a7 + (size_t)n * 3 * HW + i;
        atomicAdd(&ls[id * 3 + 0], p[0]);
        atomicAdd(&ls[id * 3 + 1], p[HW]);
        atomicAdd(&ls[id * 3 + 2], p[2 * (size_t)HW]);
        atomicAdd(&ls[96 + id], 1.0f);
    }
    __syncthreads();
    for (int i2 = threadIdx.x; i2 < 128; i2 += 256)
        if (ls[i2] != 0.f) atomicAdd(&bins[i2], ls[i2]);
}

__global__ void seg_scatter(const float* __restrict__ bins, const int* __restrict__ inst,
                            float* __restrict__ out, int HW) {
    int n = blockIdx.y;
    int i = blockIdx.x * 256 + threadIdx.x;
    if (i >= HW) return;
    int id = inst[(size_t)n * HW + i];
    float c = fmaxf(bins[96 + id], 1.0f);
    out[((size_t)n * 3 + 0) * HW + i] = bins[id * 3 + 0] / c;
    out[((size_t)n * 3 + 1) * HW + i] = bins[id * 3 + 1] / c;
    out[((size_t)n * 3 + 2) * HW + i] = bins[id * 3 + 2] / c;
}

// ---------------------------------------------------------------------------
extern "C" void kernel_launch(void* const* d_in, const int* in_sizes, int n_in,
                              void* d_out, int out_size, void* d_ws, size_t ws_size,
                              hipStream_t stream) {
    const float* x = (const float*)d_in[0];
    const int* inst = (const int*)d_in[1];
    const float* W[8];
    const float* B[8];
    for (int i = 0; i < 8; ++i) {
        W[i] = (const float*)d_in[2 + 2 * i];
        B[i] = (const float*)d_in[3 + 2 * i];
    }
    float* ws = (float*)d_ws;

    const size_t S = 25165824;  // activation arena floats
    float* a0 = ws;
    float* a1 = ws + 16777216;
    float* a2 = ws;
    float* a3 = ws + 23068672;
    float* a4 = ws;
    float* a5 = ws + 17165824;
    float* a6 = ws;
    float* a7 = ws + 23677800;
    float* ssum = ws + S;          // 5632
    float* sssum = ssum + 5632;    // 5632
    float* bins = sssum + 5632;    // 128
    float* spart = bins + 128;     // 151552
    float* sspart = spart + 151552;
    // stats offsets per layer into ssum/sssum
    const int OFF0 = 0, OFF1 = 256, OFF2 = 768, OFF3 = 1792, OFF4 = 3840, OFF5 = 4864, OFF6 = 5376;
    // partial offsets (floats) per layer: nT*P
    const int PO0 = 0, PO1 = 65536, PO2 = 98304, PO3 = 114688, PO4 = 122880, PO5 = 126976, PO6 = 135168;

    zero_buf<<<dim3(1), 256, 0, stream>>>(bins, 128);

    // L0: 7x7 reflect, 3->32, 256 (raw input). nT=256, P=256
    conv7x7<3, 3, 8, false, false><<<dim3(256, 4, 8), 256, 0, stream>>>(
        x, W[0], B[0], a0, nullptr, nullptr, 0.f, 0, spart + PO0, sspart + PO0, 256, 32, 256, 256);
    stat_reduce<<<dim3(256), 64, 0, stream>>>(spart + PO0, sspart + PO0, ssum, sssum, 256, 256, OFF0);
    // L1: 3x3 s2, 32->64, 256->128. nT=64, P=512
    conv3s2<32, 4, 8><<<dim3(64, 8, 8), 256, 0, stream>>>(
        a0, W[1], B[1], a1, ssum, sssum, 1.f / 65536.f, OFF0, spart + PO1, sspart + PO1, 512,
        64, 256, 256, 128, 128);
    stat_reduce<<<dim3(512), 64, 0, stream>>>(spart + PO1, sspart + PO1, ssum, sssum, 512, 64, OFF1);
    // L2: 3x3 s2, 64->128, 128->64. nT=16, P=1024
    conv3s2<64, 4, 8><<<dim3(16, 16, 8), 256, 0, stream>>>(
        a1, W[2], B[2], a2, ssum, sssum, 1.f / 16384.f, OFF1, spart + PO2, sspart + PO2, 1024,
        128, 128, 128, 64, 64);
    stat_reduce<<<dim3(1024), 64, 0, stream>>>(spart + PO2, sspart + PO2, ssum, sssum, 1024, 16, OFF2);
    // L3: 3x3 s2, 128->256, 64->32. nT=4, P=2048
    conv3s2<128, 4, 8><<<dim3(4, 32, 8), 256, 0, stream>>>(
        a2, W[3], B[3], a3, ssum, sssum, 1.f / 4096.f, OFF2, spart + PO3, sspart + PO3, 2048,
        256, 64, 64, 32, 32);
    stat_reduce<<<dim3(2048), 64, 0, stream>>>(spart + PO3, sspart + PO3, ssum, sssum, 2048, 4, OFF3);
    // L4: convT, 256->128, 32->63. nT=4, P=1024
    convt3s2<256, 16, 8><<<dim3(4, 16, 8), 256, 0, stream>>>(
        a3, W[4], B[4], a4, ssum, sssum, 1.f / 1024.f, OFF3, spart + PO4, sspart + PO4, 1024,
        128, 32, 32, 63, 63);
    stat_reduce<<<dim3(1024), 64, 0, stream>>>(spart + PO4, sspart + PO4, ssum, sssum, 1024, 4, OFF4);
    // L5: convT, 128->64, 63->125. nT=16, P=512
    convt3s2<128, 8, 8><<<dim3(16, 8, 8), 256, 0, stream>>>(
        a4, W[5], B[5], a5, ssum, sssum, 1.f / 3969.f, OFF4, spart + PO5, sspart + PO5, 512,
        64, 63, 63, 125, 125);
    stat_reduce<<<dim3(512), 64, 0, stream>>>(spart + PO5, sspart + PO5, ssum, sssum, 512, 16, OFF5);
    // L6: convT, 64->32, 125->249. nT=64, P=256
    convt3s2<64, 8, 8><<<dim3(64, 4, 8), 256, 0, stream>>>(
        a5, W[6], B[6], a6, ssum, sssum, 1.f / 15625.f, OFF5, spart + PO6, sspart + PO6, 256,
        32, 125, 125, 249, 249);
    stat_reduce<<<dim3(256), 64, 0, stream>>>(spart + PO6, sspart + PO6, ssum, sssum, 256, 64, OFF6);
    // L7: 7x7 reflect, 32->3, 249, norm-in + tanh (no stats out)
    conv7x7<32, 8, 3, true, true><<<dim3(256, 1, 8), 256, 0, stream>>>(
        a6, W[7], B[7], a7, ssum, sssum, 1.f / 62001.f, OFF6, nullptr, nullptr, 0, 3, 249, 249);

    // segment mean
    seg_accum<<<dim3(IDIV(62001, 256), 8), 256, 0, stream>>>(a7, inst, bins, 62001);
    seg_scatter<<<dim3(IDIV(62001, 256), 8), 256, 0, stream>>>(bins, inst, (float*)d_out, 62001);
}